// Round 2
// baseline (736.662 us; speedup 1.0000x reference)
//
#include <hip/hip_runtime.h>
#include <math.h>

#define NTOK  32768   // B*T = 4*8192
#define DDIM  2048
#define NEXP  64
#define TOPK  8
#define TPW   8       // tokens per wave
#define WPB   4       // waves per block
#define KC    64      // K-chunk staged in LDS (64*64 doubles = 32 KB)

__global__ __launch_bounds__(256, 2) void router_kernel(
    const float* __restrict__ x, const float* __restrict__ w,
    float* __restrict__ out) {
  __shared__ double wlds[KC * NEXP];  // 32 KB

  const int tid  = threadIdx.x;
  const int lane = tid & 63;                                   // = expert id
  const int wave = __builtin_amdgcn_readfirstlane(tid >> 6);   // wave-uniform
  const int tok0 = blockIdx.x * (TPW * WPB) + wave * TPW;

  double acc[TPW];
#pragma unroll
  for (int t = 0; t < TPW; ++t) acc[t] = 0.0;

  for (int c = 0; c < DDIM / KC; ++c) {
    __syncthreads();
    // stage W chunk as f64: KC*64 = 4096 floats, 256 threads -> 16 each
    const float* src = w + c * (KC * NEXP);
#pragma unroll
    for (int i = 0; i < (KC * NEXP) / 256; ++i)
      wlds[tid + i * 256] = (double)src[tid + i * 256];
    __syncthreads();

    const int kbase = c * KC;
#pragma unroll 2
    for (int d4 = 0; d4 < KC / 4; ++d4) {
      const double w0 = wlds[(d4 * 4 + 0) * NEXP + lane];
      const double w1 = wlds[(d4 * 4 + 1) * NEXP + lane];
      const double w2 = wlds[(d4 * 4 + 2) * NEXP + lane];
      const double w3 = wlds[(d4 * 4 + 3) * NEXP + lane];
#pragma unroll
      for (int t = 0; t < TPW; ++t) {
        // wave-uniform address -> scalar load path
        const float4 xv =
            *(const float4*)(x + (size_t)(tok0 + t) * DDIM + kbase + d4 * 4);
        acc[t] = fma((double)xv.x, w0, acc[t]);
        acc[t] = fma((double)xv.y, w1, acc[t]);
        acc[t] = fma((double)xv.z, w2, acc[t]);
        acc[t] = fma((double)xv.w, w3, acc[t]);
      }
    }
  }

  float* out_w = out;                          // (NTOK, 8) fp32 weights
  float* out_i = out + (size_t)NTOK * TOPK;    // (NTOK, 8) indices as float

#pragma unroll 1
  for (int t = 0; t < TPW; ++t) {
    const int tok = tok0 + t;
    const double v = acc[t];

    // full softmax over 64 experts (one value per lane), in f64
    double m = v;
#pragma unroll
    for (int off = 32; off; off >>= 1) m = fmax(m, __shfl_xor(m, off));
    const double ex = exp(v - m);
    double s = ex;
#pragma unroll
    for (int off = 32; off; off >>= 1) s += __shfl_xor(s, off);
    double pv = ex / s;  // this lane's prob; knocked out once selected

    // 8 rounds of wave argmax; tie-break: equal value -> lower index
    double selv[TOPK];
    int    seli[TOPK];
#pragma unroll
    for (int r = 0; r < TOPK; ++r) {
      double bv = pv;
      int    bi = lane;
#pragma unroll
      for (int off = 32; off; off >>= 1) {
        const double ov = __shfl_xor(bv, off);
        const int    oi = __shfl_xor(bi, off);
        const bool take = (ov > bv) || (ov == bv && oi < bi);
        bv = take ? ov : bv;
        bi = take ? oi : bi;
      }
      selv[r] = bv;
      seli[r] = bi;
      if (lane == bi) pv = -1.0e300;
    }

    // renormalize: softmax over the 8 selected probabilities
    const double mm = selv[0];  // largest
    double ssum = 0.0;
#pragma unroll
    for (int k = 0; k < TOPK; ++k) ssum += exp(selv[k] - mm);

    double myv = selv[0];
    int    myi = seli[0];
#pragma unroll
    for (int k = 1; k < TOPK; ++k) {
      if (lane == k) { myv = selv[k]; myi = seli[k]; }
    }
    if (lane < TOPK) {
      out_w[(size_t)tok * TOPK + lane] = (float)(exp(myv - mm) / ssum);
      out_i[(size_t)tok * TOPK + lane] = (float)myi;
    }
  }
}

extern "C" void kernel_launch(void* const* d_in, const int* in_sizes, int n_in,
                              void* d_out, int out_size, void* d_ws, size_t ws_size,
                              hipStream_t stream) {
  const float* x = (const float*)d_in[0];
  const float* w = (const float*)d_in[1];
  router_kernel<<<dim3(NTOK / (TPW * WPB)), dim3(256), 0, stream>>>(
      x, w, (float*)d_out);
}